// Round 2
// baseline (128.849 us; speedup 1.0000x reference)
//
#include <hip/hip_runtime.h>
#include <math.h>

// GConvLSTM cell (graph part is dead code in the reference).
// Per node n (N=1e6): g[64] = x[8] @ Wx[8x64] + bx + h[16] @ Wh[16x64] + bh
//   i = sig(g[0:16]  + w_peep[0]*c + b_gates[0])
//   f = sig(g[16:32] + w_peep[1]*c + b_gates[1])
//   t = tanh(g[32:48] + b_gates[2])
//   c_new = f*c + i*t
//   o = sig(g[48:64] + w_peep[2]*c_new + b_gates[3])
//   h_new = o * tanh(c_new)
//   out = relu(h_new) @ W_lin[16x1] + b_lin
// d_out layout: [N] out | [N*16] h_new | [N*16] c_new

__device__ __forceinline__ float sig1(float v) {
    return __fdividef(1.0f, 1.0f + __expf(-v));
}
__device__ __forceinline__ float tanh1(float v) {
    // tanh(x) = 1 - 2/(exp(2x)+1); saturates correctly at +/-inf
    return 1.0f - __fdividef(2.0f, __expf(2.0f * v) + 1.0f);
}

__device__ __forceinline__ float4 sig4(float4 v) {
    return make_float4(sig1(v.x), sig1(v.y), sig1(v.z), sig1(v.w));
}
__device__ __forceinline__ float4 tanh4v(float4 v) {
    return make_float4(tanh1(v.x), tanh1(v.y), tanh1(v.z), tanh1(v.w));
}
__device__ __forceinline__ float4 add4(float4 a, float4 b) {
    return make_float4(a.x + b.x, a.y + b.y, a.z + b.z, a.w + b.w);
}
__device__ __forceinline__ float4 mul4(float4 a, float4 b) {
    return make_float4(a.x * b.x, a.y * b.y, a.z * b.z, a.w * b.w);
}
// scalar * vec + vec
__device__ __forceinline__ float4 fmas4(float s, float4 a, float4 b) {
    return make_float4(fmaf(s, a.x, b.x), fmaf(s, a.y, b.y), fmaf(s, a.z, b.z), fmaf(s, a.w, b.w));
}
// vec * vec + vec
__device__ __forceinline__ float4 fmav4(float4 a, float4 b, float4 c) {
    return make_float4(fmaf(a.x, b.x, c.x), fmaf(a.y, b.y, c.y), fmaf(a.z, b.z, c.z), fmaf(a.w, b.w, c.w));
}
__device__ __forceinline__ float4 relu4(float4 a) {
    return make_float4(fmaxf(a.x, 0.f), fmaxf(a.y, 0.f), fmaxf(a.z, 0.f), fmaxf(a.w, 0.f));
}

__global__ __launch_bounds__(256) void gconv_lstm_kernel(
    const float* __restrict__ x,       // N x 8
    const float* __restrict__ h,       // N x 16
    const float* __restrict__ c,       // N x 16
    const float* __restrict__ Wx,      // 8 x 64
    const float* __restrict__ bx,      // 64
    const float* __restrict__ Wh,      // 16 x 64
    const float* __restrict__ bh,      // 64
    const float* __restrict__ w_peep,  // 3 x 16
    const float* __restrict__ b_gates, // 4 x 16
    const float* __restrict__ W_lin,   // 16
    const float* __restrict__ b_lin,   // 1
    float* __restrict__ dout,
    int n)
{
    __shared__ float sWx[8 * 64];
    __shared__ float sWh[16 * 64];
    __shared__ float sBias[64];      // bx + bh fused
    __shared__ float sPeep[3 * 16];
    __shared__ float sBg[4 * 16];
    __shared__ float sWlin[16];
    __shared__ float sBlin;

    const int tid = threadIdx.x;
    for (int idx = tid; idx < 512; idx += 256)  sWx[idx] = Wx[idx];
    for (int idx = tid; idx < 1024; idx += 256) sWh[idx] = Wh[idx];
    // NOTE: explicit lower bounds on every range — an earlier else-if chain
    // let tid in [112,128) write sBg[-16..-1], clobbering sPeep (w_peep[2]).
    if (tid < 64)                        sBias[tid]       = bx[tid] + bh[tid];
    if (tid >= 64  && tid < 64 + 48)     sPeep[tid - 64]  = w_peep[tid - 64];
    if (tid >= 128 && tid < 128 + 64)    sBg[tid - 128]   = b_gates[tid - 128];
    if (tid >= 192 && tid < 192 + 16)    sWlin[tid - 192] = W_lin[tid - 192];
    if (tid == 255)                      sBlin            = b_lin[0];
    __syncthreads();

    const int i = blockIdx.x * 256 + tid;
    if (i >= n) return;

    const float4* sWx4   = reinterpret_cast<const float4*>(sWx);
    const float4* sWh4   = reinterpret_cast<const float4*>(sWh);
    const float4* sBias4 = reinterpret_cast<const float4*>(sBias);
    const float4* sPeep4 = reinterpret_cast<const float4*>(sPeep);
    const float4* sBg4   = reinterpret_cast<const float4*>(sBg);
    const float4* sWlin4 = reinterpret_cast<const float4*>(sWlin);

    // load per-node inputs, vectorized
    float xk[8], hk[16];
    {
        const float4* xp = reinterpret_cast<const float4*>(x + (size_t)i * 8);
        float4 a0 = xp[0], a1 = xp[1];
        xk[0] = a0.x; xk[1] = a0.y; xk[2] = a0.z; xk[3] = a0.w;
        xk[4] = a1.x; xk[5] = a1.y; xk[6] = a1.z; xk[7] = a1.w;
        const float4* hp = reinterpret_cast<const float4*>(h + (size_t)i * 16);
        #pragma unroll
        for (int q = 0; q < 4; ++q) {
            float4 hv = hp[q];
            hk[q * 4 + 0] = hv.x; hk[q * 4 + 1] = hv.y;
            hk[q * 4 + 2] = hv.z; hk[q * 4 + 3] = hv.w;
        }
    }
    const float4* cp = reinterpret_cast<const float4*>(c + (size_t)i * 16);

    float4* hout = reinterpret_cast<float4*>(dout + (size_t)n + (size_t)i * 16);
    float4* cout = reinterpret_cast<float4*>(dout + (size_t)n * 17 + (size_t)i * 16);

    float4 acc4 = make_float4(0.f, 0.f, 0.f, 0.f);

    // process d in 4 groups of 4 to keep register pressure low
    #pragma unroll
    for (int dg = 0; dg < 4; ++dg) {
        float4 gi = sBias4[dg];
        float4 gf = sBias4[4 + dg];
        float4 gc = sBias4[8 + dg];
        float4 go = sBias4[12 + dg];
        #pragma unroll
        for (int k = 0; k < 8; ++k) {
            float xv = xk[k];
            gi = fmas4(xv, sWx4[k * 16 + dg],      gi);
            gf = fmas4(xv, sWx4[k * 16 + 4 + dg],  gf);
            gc = fmas4(xv, sWx4[k * 16 + 8 + dg],  gc);
            go = fmas4(xv, sWx4[k * 16 + 12 + dg], go);
        }
        #pragma unroll
        for (int k = 0; k < 16; ++k) {
            float hv = hk[k];
            gi = fmas4(hv, sWh4[k * 16 + dg],      gi);
            gf = fmas4(hv, sWh4[k * 16 + 4 + dg],  gf);
            gc = fmas4(hv, sWh4[k * 16 + 8 + dg],  gc);
            go = fmas4(hv, sWh4[k * 16 + 12 + dg], go);
        }

        float4 cv = cp[dg];
        float4 iv = sig4(add4(fmav4(sPeep4[dg],     cv, gi), sBg4[dg]));
        float4 fv = sig4(add4(fmav4(sPeep4[4 + dg], cv, gf), sBg4[4 + dg]));
        float4 tv = tanh4v(add4(gc, sBg4[8 + dg]));
        float4 cn = add4(mul4(fv, cv), mul4(iv, tv));
        float4 ov = sig4(add4(fmav4(sPeep4[8 + dg], cn, go), sBg4[12 + dg]));
        float4 hn = mul4(ov, tanh4v(cn));

        hout[dg] = hn;
        cout[dg] = cn;
        acc4 = fmav4(relu4(hn), sWlin4[dg], acc4);
    }

    dout[i] = acc4.x + acc4.y + acc4.z + acc4.w + sBlin;
}

extern "C" void kernel_launch(void* const* d_in, const int* in_sizes, int n_in,
                              void* d_out, int out_size, void* d_ws, size_t ws_size,
                              hipStream_t stream) {
    const float* x       = (const float*)d_in[0];
    // d_in[1] = edge_index (int64, unused), d_in[2] = edge_attr (unused)
    const float* h       = (const float*)d_in[3];
    const float* c       = (const float*)d_in[4];
    const float* Wx      = (const float*)d_in[5];
    const float* bx      = (const float*)d_in[6];
    const float* Wh      = (const float*)d_in[7];
    const float* bh      = (const float*)d_in[8];
    const float* w_peep  = (const float*)d_in[9];
    const float* b_gates = (const float*)d_in[10];
    const float* W_lin   = (const float*)d_in[11];
    const float* b_lin   = (const float*)d_in[12];
    float* out = (float*)d_out;

    const int n = in_sizes[0] / 8;  // N = 1,000,000
    const int blocks = (n + 255) / 256;
    gconv_lstm_kernel<<<blocks, 256, 0, stream>>>(
        x, h, c, Wx, bx, Wh, bh, w_peep, b_gates, W_lin, b_lin, out, n);
}

// Round 3
// 76.586 us; speedup vs baseline: 1.6824x; 1.6824x over previous
//
#include <hip/hip_runtime.h>
#include <math.h>

// GConvLSTM cell via MFMA (graph inputs are dead code in the reference).
// Gate GEMM: g[node][0:64] = [x(8) | h(16) | pad8] @ W(32x64) + (bx+bh),
// computed with mfma_f32_16x16x32_bf16: one wave = 16 nodes, 4 MFMAs (one per
// gate tile of 16 cols), K=32 in a single step. Weights live in 16 VGPRs of
// B-fragments loaded once per block; bias is pre-loaded into the accumulator.
// Epilogue (peephole sigmoid/tanh, c_new/h_new, out-projection) is f32 VALU on
// the D-fragment layout: lane holds (d = lane&15, nodes rb..rb+3), so all
// h_new/c_new stores are dense 64B segments -> no write amplification.
// d_out layout: [N] out | [N*16] h_new | [N*16] c_new.  Requires n % 16 == 0.

typedef short bf16x8 __attribute__((ext_vector_type(8)));
typedef float f32x4 __attribute__((ext_vector_type(4)));

__device__ __forceinline__ short f2bf(float f) {
    union { float f; unsigned u; } v; v.f = f;
    unsigned r = (v.u + 0x7FFFu + ((v.u >> 16) & 1u)) >> 16;  // RNE
    return (short)r;
}
__device__ __forceinline__ float sig1(float v) {
    return __fdividef(1.0f, 1.0f + __expf(-v));
}
__device__ __forceinline__ float tanh1(float v) {
    return 1.0f - __fdividef(2.0f, __expf(2.0f * v) + 1.0f);
}

#define IW 8                      // 64-node tiles per block
#define NODES_PER_BLOCK (64 * IW) // 512

__global__ __launch_bounds__(256) void lstm_mfma_kernel(
    const float* __restrict__ x,       // N x 8
    const float* __restrict__ h,       // N x 16
    const float* __restrict__ c,       // N x 16
    const float* __restrict__ Wx,      // 8 x 64
    const float* __restrict__ bx,      // 64
    const float* __restrict__ Wh,      // 16 x 64
    const float* __restrict__ bh,      // 64
    const float* __restrict__ w_peep,  // 3 x 16
    const float* __restrict__ b_gates, // 4 x 16
    const float* __restrict__ W_lin,   // 16
    const float* __restrict__ b_lin,   // 1
    float* __restrict__ dout,
    int n)
{
    const int lane = threadIdx.x & 63;
    const int wave = threadIdx.x >> 6;
    const int d  = lane & 15;   // output dim within gate / A row offset
    const int kb = lane >> 4;   // k-block (8 k's each)

    // ---- B fragments: bfrag[t][e] = W[kb*8+e][t*16+d], W = [Wx; Wh; 0pad]
    bf16x8 bfrag[4];
    #pragma unroll
    for (int t = 0; t < 4; ++t) {
        #pragma unroll
        for (int e = 0; e < 8; ++e) {
            const int r = kb * 8 + e;
            float w = 0.0f;
            if (r < 8)        w = Wx[r * 64 + t * 16 + d];
            else if (r < 24)  w = Wh[(r - 8) * 64 + t * 16 + d];
            bfrag[t][e] = f2bf(w);
        }
    }

    // ---- per-lane epilogue constants (indexed by d)
    float bias[4];
    #pragma unroll
    for (int t = 0; t < 4; ++t) bias[t] = bx[t * 16 + d] + bh[t * 16 + d];
    const float p0  = w_peep[d],      p1  = w_peep[16 + d], p2 = w_peep[32 + d];
    const float bg0 = b_gates[d],     bg1 = b_gates[16 + d];
    const float bg2 = b_gates[32 + d], bg3 = b_gates[48 + d];
    const float wl  = W_lin[d];
    const float bl  = b_lin[0];

    const size_t blockBase = (size_t)blockIdx.x * NODES_PER_BLOCK;

    for (int it = 0; it < IW; ++it) {
        const size_t gb = blockBase + (size_t)it * 64 + (size_t)wave * 16;
        if (gb >= (size_t)n) break;   // n % 16 == 0: groups all-or-nothing
        const int node = (int)gb + d;

        // ---- A fragment: row = d (node), k = kb*8+e; [x(8)|h(16)|zeros]
        const float* ab = (kb == 0) ? (x + (size_t)node * 8)
                                    : (h + (size_t)node * 16 + ((kb & 1) ? 0 : 8));
        float4 a0 = *reinterpret_cast<const float4*>(ab);
        float4 a1 = *reinterpret_cast<const float4*>(ab + 4);
        if (kb == 3) { a0 = make_float4(0,0,0,0); a1 = make_float4(0,0,0,0); }
        bf16x8 afrag;
        afrag[0] = f2bf(a0.x); afrag[1] = f2bf(a0.y);
        afrag[2] = f2bf(a0.z); afrag[3] = f2bf(a0.w);
        afrag[4] = f2bf(a1.x); afrag[5] = f2bf(a1.y);
        afrag[6] = f2bf(a1.z); afrag[7] = f2bf(a1.w);

        // ---- gate GEMM, bias pre-loaded in C
        f32x4 accI = {bias[0], bias[0], bias[0], bias[0]};
        f32x4 accF = {bias[1], bias[1], bias[1], bias[1]};
        f32x4 accC = {bias[2], bias[2], bias[2], bias[2]};
        f32x4 accO = {bias[3], bias[3], bias[3], bias[3]};
        accI = __builtin_amdgcn_mfma_f32_16x16x32_bf16(afrag, bfrag[0], accI, 0, 0, 0);
        accF = __builtin_amdgcn_mfma_f32_16x16x32_bf16(afrag, bfrag[1], accF, 0, 0, 0);
        accC = __builtin_amdgcn_mfma_f32_16x16x32_bf16(afrag, bfrag[2], accC, 0, 0, 0);
        accO = __builtin_amdgcn_mfma_f32_16x16x32_bf16(afrag, bfrag[3], accO, 0, 0, 0);

        // ---- epilogue: lane holds nodes rb..rb+3 at dim d (D-layout:
        //      col=lane&15, row=(lane>>4)*4+e)
        const size_t rb = gb + (size_t)kb * 4;
        const float* crow = c + rb * 16 + d;
        float* hrow = dout + (size_t)n      + rb * 16 + d;
        float* crw  = dout + (size_t)n * 17 + rb * 16 + d;

        float osum[4];
        #pragma unroll
        for (int e = 0; e < 4; ++e) {
            const float cv = crow[e * 16];
            const float iv = sig1(accI[e] + p0 * cv + bg0);
            const float fv = sig1(accF[e] + p1 * cv + bg1);
            const float tv = tanh1(accC[e] + bg2);
            const float cn = fv * cv + iv * tv;
            const float ov = sig1(accO[e] + p2 * cn + bg3);
            const float hn = ov * tanh1(cn);
            hrow[e * 16] = hn;
            crw[e * 16]  = cn;
            osum[e] = fmaxf(hn, 0.0f) * wl;
        }

        // ---- out projection: reduce over d (16 lanes per group)
        #pragma unroll
        for (int m = 1; m < 16; m <<= 1) {
            #pragma unroll
            for (int e = 0; e < 4; ++e) osum[e] += __shfl_xor(osum[e], m, 16);
        }
        if (d == 0) {
            #pragma unroll
            for (int e = 0; e < 4; ++e) dout[rb + e] = osum[e] + bl;
        }
    }
}

extern "C" void kernel_launch(void* const* d_in, const int* in_sizes, int n_in,
                              void* d_out, int out_size, void* d_ws, size_t ws_size,
                              hipStream_t stream) {
    const float* x       = (const float*)d_in[0];
    // d_in[1] = edge_index (int64, unused), d_in[2] = edge_attr (unused)
    const float* h       = (const float*)d_in[3];
    const float* c       = (const float*)d_in[4];
    const float* Wx      = (const float*)d_in[5];
    const float* bx      = (const float*)d_in[6];
    const float* Wh      = (const float*)d_in[7];
    const float* bh      = (const float*)d_in[8];
    const float* w_peep  = (const float*)d_in[9];
    const float* b_gates = (const float*)d_in[10];
    const float* W_lin   = (const float*)d_in[11];
    const float* b_lin   = (const float*)d_in[12];
    float* out = (float*)d_out;

    const int n = in_sizes[0] / 8;  // N = 1,000,000
    const int blocks = (n + NODES_PER_BLOCK - 1) / NODES_PER_BLOCK;
    lstm_mfma_kernel<<<blocks, 256, 0, stream>>>(
        x, h, c, Wx, bx, Wh, bh, w_peep, b_gates, W_lin, b_lin, out, n);
}

// Round 4
// 67.939 us; speedup vs baseline: 1.8966x; 1.1273x over previous
//
#include <hip/hip_runtime.h>
#include <hip/hip_bf16.h>
#include <math.h>

// GConvLSTM cell via MFMA (graph inputs are dead code in the reference).
// Gate GEMM: g[node][0:64] = [x(8) | h(16) | pad8] @ W(32x64) + (bx+bh+b_gates),
// one wave = 16 nodes, 4x mfma_f32_16x16x32_bf16 (one per gate).
// D-layout (verified R3): lane holds (d = lane&15, nodes rb..rb+3, rb = gb + (lane>>4)*4).
// Epilogue f32 VALU on that layout -> dense 64B-segment stores, no amplification.
// VALU diet vs R3: native __bf16 casts (v_cvt_pk_bf16_f32), hoisted 32-bit
// offsets bumped by constants, no kb==3 zeroing (B rows 24..31 are exactly 0,
// so garbage A there contributes 0), b_gates folded into MFMA bias, exp2-based
// sigmoid/tanh, exact trip count for full blocks.
// d_out layout: [N] out | [N*16] h_new | [N*16] c_new.  Requires n % 16 == 0.

typedef short bf16x8 __attribute__((ext_vector_type(8)));
typedef float f32x4 __attribute__((ext_vector_type(4)));

#define LOG2E 1.44269504088896f

__device__ __forceinline__ float sig1(float v) {
    return __builtin_amdgcn_rcpf(1.0f + __builtin_amdgcn_exp2f(-LOG2E * v));
}
__device__ __forceinline__ float tanh1(float v) {
    // tanh(x) = 1 - 2/(exp2(2x*log2e)+1); saturates correctly
    return 1.0f - 2.0f * __builtin_amdgcn_rcpf(__builtin_amdgcn_exp2f((2.0f * LOG2E) * v) + 1.0f);
}
__device__ __forceinline__ f32x4 sig4(f32x4 v) {
    f32x4 r; r[0]=sig1(v[0]); r[1]=sig1(v[1]); r[2]=sig1(v[2]); r[3]=sig1(v[3]); return r;
}
__device__ __forceinline__ f32x4 tanh4(f32x4 v) {
    f32x4 r; r[0]=tanh1(v[0]); r[1]=tanh1(v[1]); r[2]=tanh1(v[2]); r[3]=tanh1(v[3]); return r;
}
__device__ __forceinline__ short f2bf(float f) {
    __bf16 b = (__bf16)f;          // compiler emits v_cvt_pk_bf16_f32 for pairs
    short s; __builtin_memcpy(&s, &b, 2); return s;
}
__device__ __forceinline__ f32x4 max4z(f32x4 a) {
    f32x4 r; r[0]=fmaxf(a[0],0.f); r[1]=fmaxf(a[1],0.f); r[2]=fmaxf(a[2],0.f); r[3]=fmaxf(a[3],0.f); return r;
}

#define IW 8                       // 64-node tiles per block
#define NPB (64 * IW)              // 512 nodes per block

__global__ __launch_bounds__(256) void lstm_mfma_kernel(
    const float* __restrict__ x,       // N x 8
    const float* __restrict__ h,       // N x 16
    const float* __restrict__ c,       // N x 16
    const float* __restrict__ Wx,      // 8 x 64
    const float* __restrict__ bx,      // 64
    const float* __restrict__ Wh,      // 16 x 64
    const float* __restrict__ bh,      // 64
    const float* __restrict__ w_peep,  // 3 x 16
    const float* __restrict__ b_gates, // 4 x 16
    const float* __restrict__ W_lin,   // 16
    const float* __restrict__ b_lin,   // 1
    float* __restrict__ dout,
    int n)
{
    const int lane = threadIdx.x & 63;
    const int wave = threadIdx.x >> 6;
    const int d  = lane & 15;   // output dim within gate / A row offset
    const int kb = lane >> 4;   // k-block (8 k's each)

    // ---- B fragments: bfrag[t][e] = W[kb*8+e][t*16+d], W = [Wx; Wh; 0pad]
    // Rows 24..31 MUST be exactly 0 (kb==3 A-frag is garbage and relies on it).
    bf16x8 bfrag[4];
    #pragma unroll
    for (int t = 0; t < 4; ++t) {
        #pragma unroll
        for (int e = 0; e < 8; ++e) {
            const int r = kb * 8 + e;
            float w = 0.0f;
            if (r < 8)        w = Wx[r * 64 + t * 16 + d];
            else if (r < 24)  w = Wh[(r - 8) * 64 + t * 16 + d];
            bfrag[t][e] = f2bf(w);
        }
    }

    // ---- per-lane epilogue constants (b_gates folded into MFMA bias)
    const float biasI = bx[d]      + bh[d]      + b_gates[d];
    const float biasF = bx[16 + d] + bh[16 + d] + b_gates[16 + d];
    const float biasC = bx[32 + d] + bh[32 + d] + b_gates[32 + d];
    const float biasO = bx[48 + d] + bh[48 + d] + b_gates[48 + d];
    const float p0 = w_peep[d], p1 = w_peep[16 + d], p2 = w_peep[32 + d];
    const float wl = W_lin[d];
    const float bl = b_lin[0];

    const unsigned blockBase = (unsigned)blockIdx.x * NPB;
    const unsigned gb0   = blockBase + (unsigned)wave * 16u;  // wave's first node
    const unsigned node0 = gb0 + (unsigned)d;

    // per-lane A pointer: x rows for kb==0, h rows otherwise (kb==3 garbage-ok)
    const float* aptr;
    unsigned astride;
    if (kb == 0) { aptr = x + (size_t)node0 * 8;                        astride = 64u * 8;  }
    else         { aptr = h + (size_t)node0 * 16 + ((kb == 2) ? 8 : 0); astride = 64u * 16; }

    unsigned co = (gb0 + (unsigned)kb * 4u) * 16u + (unsigned)d; // c/h_new/c_new offset
    unsigned ro =  gb0 + (unsigned)kb * 4u;                      // out offset
    float* hob = dout + (size_t)n;        // h_new base
    float* cob = dout + (size_t)n * 17;   // c_new base

#define BODY                                                                   \
    {                                                                          \
        float4 a0 = *reinterpret_cast<const float4*>(aptr);                    \
        float4 a1 = *reinterpret_cast<const float4*>(aptr + 4);                \
        bf16x8 af;                                                             \
        af[0] = f2bf(a0.x); af[1] = f2bf(a0.y);                                \
        af[2] = f2bf(a0.z); af[3] = f2bf(a0.w);                                \
        af[4] = f2bf(a1.x); af[5] = f2bf(a1.y);                                \
        af[6] = f2bf(a1.z); af[7] = f2bf(a1.w);                                \
        f32x4 accI = {biasI, biasI, biasI, biasI};                             \
        f32x4 accF = {biasF, biasF, biasF, biasF};                             \
        f32x4 accC = {biasC, biasC, biasC, biasC};                             \
        f32x4 accO = {biasO, biasO, biasO, biasO};                             \
        accI = __builtin_amdgcn_mfma_f32_16x16x32_bf16(af, bfrag[0], accI, 0, 0, 0); \
        accF = __builtin_amdgcn_mfma_f32_16x16x32_bf16(af, bfrag[1], accF, 0, 0, 0); \
        accC = __builtin_amdgcn_mfma_f32_16x16x32_bf16(af, bfrag[2], accC, 0, 0, 0); \
        accO = __builtin_amdgcn_mfma_f32_16x16x32_bf16(af, bfrag[3], accO, 0, 0, 0); \
        f32x4 cv; cv[0] = c[co]; cv[1] = c[co + 16];                           \
        cv[2] = c[co + 32]; cv[3] = c[co + 48];                                \
        f32x4 iv = sig4(p0 * cv + accI);                                       \
        f32x4 fv = sig4(p1 * cv + accF);                                       \
        f32x4 tv = tanh4(accC);                                                \
        f32x4 cn = fv * cv + iv * tv;                                          \
        f32x4 ov = sig4(p2 * cn + accO);                                       \
        f32x4 hn = ov * tanh4(cn);                                             \
        hob[co] = hn[0]; hob[co + 16] = hn[1];                                 \
        hob[co + 32] = hn[2]; hob[co + 48] = hn[3];                            \
        cob[co] = cn[0]; cob[co + 16] = cn[1];                                 \
        cob[co + 32] = cn[2]; cob[co + 48] = cn[3];                            \
        f32x4 os = max4z(hn) * wl;                                             \
        _Pragma("unroll")                                                      \
        for (int m = 1; m < 16; m <<= 1) {                                     \
            os[0] += __shfl_xor(os[0], m, 16);                                 \
            os[1] += __shfl_xor(os[1], m, 16);                                 \
            os[2] += __shfl_xor(os[2], m, 16);                                 \
            os[3] += __shfl_xor(os[3], m, 16);                                 \
        }                                                                      \
        if (d == 0) {                                                          \
            dout[ro + 0] = os[0] + bl; dout[ro + 1] = os[1] + bl;              \
            dout[ro + 2] = os[2] + bl; dout[ro + 3] = os[3] + bl;              \
        }                                                                      \
        aptr += astride; co += 1024u; ro += 64u;                               \
    }

    if (blockBase + NPB <= (unsigned)n) {
        // full block: exact trip count, no bounds checks
        for (int it = 0; it < IW; ++it) BODY
    } else {
        // tail block (at most one): group-granular bounds check (n % 16 == 0)
        for (int it = 0; it < IW; ++it) {
            if (gb0 + (unsigned)(it * 64) >= (unsigned)n) break;
            BODY
        }
    }
#undef BODY
}

extern "C" void kernel_launch(void* const* d_in, const int* in_sizes, int n_in,
                              void* d_out, int out_size, void* d_ws, size_t ws_size,
                              hipStream_t stream) {
    const float* x       = (const float*)d_in[0];
    // d_in[1] = edge_index (int64, unused), d_in[2] = edge_attr (unused)
    const float* h       = (const float*)d_in[3];
    const float* c       = (const float*)d_in[4];
    const float* Wx      = (const float*)d_in[5];
    const float* bx      = (const float*)d_in[6];
    const float* Wh      = (const float*)d_in[7];
    const float* bh      = (const float*)d_in[8];
    const float* w_peep  = (const float*)d_in[9];
    const float* b_gates = (const float*)d_in[10];
    const float* W_lin   = (const float*)d_in[11];
    const float* b_lin   = (const float*)d_in[12];
    float* out = (float*)d_out;

    const int n = in_sizes[0] / 8;  // N = 1,000,000
    const int blocks = (n + NPB - 1) / NPB;
    lstm_mfma_kernel<<<blocks, 256, 0, stream>>>(
        x, h, c, Wx, bx, Wh, bh, w_peep, b_gates, W_lin, b_lin, out, n);
}